// Round 15
// baseline (1289.487 us; speedup 1.0000x reference)
//
#include <hip/hip_runtime.h>
#include <math.h>

// ---------------------------------------------------------------------------
// SNN forward, Round-15: fully pipelined single fused launch.
//   3 "front" WGs/batch: conv1(x)+pool+lif0 (oc-split 10/10/10, independent,
//     thread=(oc,py,dy) 2058 FMA/step), publish z0 spike bitmasks as 48
//     tagged u64 words/step (384B control data — proven transport).
//   8 conv2 WGs/batch: poll z0, expand, conv2+pool+lif2, publish z2 (as r11).
//   20 rec stripe WGs/batch: round-13 poll (early-poll REVERTED — r14 showed
//     TOP-issued loads land stale and cost an extra LLC round trip).
//   1 merged reader WG/batch (both roles).
// Grid = 32*(3+8+20+1) = 1024 WGs = exactly 4/CU co-resident; fronts poll
// nothing -> deadlock-free. conv1_pool, c1buf, BP loop deleted.
// ---------------------------------------------------------------------------

#define BATCH 32
#define TSTEPS 150
#define ZSEQN 70
#define HID1 512
#define HID2 1024
#define K1CAT 582           // rows: [rec(512) | conv(70)]
#define K2CAT 1094          // rows: [rec(1024) | conv(70)]

#define N_W1T  (K1CAT*HID1)           // 297,984
#define N_W2T  (K2CAT*HID2)           // 1,120,256

#define A1_U64  (BATCH*TSTEPS*32)     // 153,600
#define A0_U64  (BATCH*TSTEPS*16)     // 76,800
#define AC_U64  (BATCH*TSTEPS*8)      // 38,400
#define AZ_U64  (BATCH*TSTEPS*48)     // 230,400 (z0 masks, 3 fronts x 16 words)
#define N_ARCH_U64 (A1_U64+A0_U64+AC_U64+AZ_U64)   // 499,200 u64 = 4 MB

typedef unsigned long long u64;

// -------------------------------------------------------------------- K0 ---
__global__ void setup_misc(const float* __restrict__ l1_in_w,
                           const float* __restrict__ l1_rec_w,
                           const float* __restrict__ cl_in_w,
                           const float* __restrict__ cl_rec_w,
                           float* __restrict__ w1t,
                           float* __restrict__ w2t,
                           u64* __restrict__ arch) {
    int idx = blockIdx.x * blockDim.x + threadIdx.x;
    int stride = gridDim.x * blockDim.x;
    for (int e = idx; e < N_W1T; e += stride) {
        int j = e / HID1, o = e - j * HID1;
        w1t[e] = (j < HID1) ? l1_rec_w[o * HID1 + j] : l1_in_w[o * 70 + (j - HID1)];
    }
    for (int e = idx; e < N_W2T; e += stride) {
        int j = e / HID2, o = e - j * HID2;
        w2t[e] = (j < HID2) ? cl_rec_w[o * HID2 + j] : cl_in_w[o * 70 + (j - HID2)];
    }
    for (int e = idx; e < N_ARCH_U64; e += stride) arch[e] = 0ull;
}

// ------------------------------------------------------------- helpers ---
__device__ __forceinline__ float4 f4add(float4 a, const float4 b) {
    a.x += b.x; a.y += b.y; a.z += b.z; a.w += b.w; return a;
}
__device__ __forceinline__ void ast64(u64* p, u64 v) {
    __hip_atomic_store(p, v, __ATOMIC_RELAXED, __HIP_MEMORY_SCOPE_AGENT);
}
__device__ __forceinline__ u64 ald64(const u64* p) {
    return __hip_atomic_load((u64*)p, __ATOMIC_RELAXED, __HIP_MEMORY_SCOPE_AGENT);
}

// ---------------------------------------------------------- front body ---
// conv1(7x7)+maxpool3+lif0 for ocs [10h,10h+10). thread<210 = (ocl,py,dy)
// computes one conv row (21 cols) per step; thread<70 = (ocl,py) pools and
// owns lif0 state for 7 px. Publishes 16 tagged words (490 bits local).
// Arithmetic orders verbatim from the verified conv1_pool / conv_body.
__device__ __forceinline__ void front_body(int h, int b,
        const float* __restrict__ x, const float* __restrict__ w1,
        const float* __restrict__ b1, u64* __restrict__ az, float* smem) {
    float* img  = smem;                        // 2380 (2 x 34 rows x 35 pad)
    float* w1s  = smem + 2380;                 // 980
    float* part = smem + 3360;                 // 4410 (210 rows x 21)
    unsigned int* zbu = (unsigned int*)(smem + 7770);   // 70

    const int t = threadIdx.x;
    const int lane = t & 63, wv = t >> 6;
    const int oc0 = 10 * h;
    // conv mapping
    const int ocl = t / 21, rem = t - ocl * 21;
    const int cpy = rem / 3, cdy = rem - cpy * 3;
    const int cy = 3 * cpy + cdy;
    // pool / lif0 mapping (t < 70)
    const float b1r = (t < 70) ? b1[oc0 + t / 7] : 0.f;

    for (int e = t; e < 980; e += 256) w1s[e] = w1[oc0 * 98 + e];
    float v0r[7], i0r[7];
    #pragma unroll
    for (int k = 0; k < 7; ++k) { v0r[k] = 0.f; i0r[k] = 0.f; }

    const float* xb = x + (size_t)b * TSTEPS * 2312;
    float pf[10];
    #pragma unroll
    for (int k = 0; k < 10; ++k) {
        int e = t + k * 256;
        pf[k] = (e < 2312) ? xb[e] : 0.f;
    }

    for (int tt = 0; tt < TSTEPS; ++tt) {
        // ---- TOP: lif0 spike decision (state t-1) + i decay; pack bits ----
        if (t < 70) {
            unsigned zbits = 0;
            #pragma unroll
            for (int px = 0; px < 7; ++px) {
                float vd = v0r[px] + 0.1f * (i0r[px] - v0r[px]);
                bool sp = (vd > 1.0f);
                v0r[px] = sp ? 0.f : vd;
                i0r[px] = i0r[px] - 0.2f * i0r[px];
                zbits |= (sp ? 1u : 0u) << px;
            }
            zbu[t] = zbits;
        }
        __syncthreads();                                   // F0: zbu ready
        if (wv == 0 && lane < 16) {
            unsigned val = 0;
            int tl0 = (32 * lane) / 7, tl1 = (32 * lane + 31) / 7;
            for (int tl = tl0; tl <= tl1 && tl < 70; ++tl) {
                int sh = 7 * tl - 32 * lane;
                unsigned zb = zbu[tl] & 0x7Fu;
                val |= (sh >= 0) ? (zb << sh) : (zb >> (-sh));
            }
            ast64(az + (size_t)tt * 48 + h * 16 + lane,
                  (((u64)(tt + 1)) << 32) | val);
        }
        // stage img(tt) from pf regs; issue pf(tt+1)
        #pragma unroll
        for (int k = 0; k < 10; ++k) {
            int e = t + k * 256;
            if (e < 2312) {
                int ic = e / 1156, rr = e - ic * 1156;
                img[ic * 1190 + (rr / 34) * 35 + (rr - 34 * (rr / 34))] = pf[k];
            }
        }
        if (tt + 1 < TSTEPS) {
            const float* xn = xb + (size_t)(tt + 1) * 2312;
            #pragma unroll
            for (int k = 0; k < 10; ++k) {
                int e = t + k * 256;
                pf[k] = (e < 2312) ? xn[e] : 0.f;
            }
        }
        __syncthreads();                                   // F1: img ready
        // ---- conv1 row (verbatim order: ic, ky, kx, cx) ----
        if (t < 210) {
            float acc[21];
            #pragma unroll
            for (int j = 0; j < 21; ++j) acc[j] = 0.f;
            #pragma unroll
            for (int ic = 0; ic < 2; ++ic) {
                const float* irow0 = &img[ic * 1190];
                const float* wrow = &w1s[(ocl * 2 + ic) * 49];
                #pragma unroll
                for (int ky = 0; ky < 7; ++ky) {
                    const float* ir = &irow0[(cy + ky) * 35];
                    float r[27];
                    #pragma unroll
                    for (int j = 0; j < 27; ++j) r[j] = ir[j];
                    #pragma unroll
                    for (int kx = 0; kx < 7; ++kx) {
                        float w = wrow[ky * 7 + kx];
                        #pragma unroll
                        for (int cx = 0; cx < 21; ++cx)
                            acc[cx] = fmaf(r[cx + kx], w, acc[cx]);
                    }
                }
            }
            #pragma unroll
            for (int cx = 0; cx < 21; ++cx) part[t * 21 + cx] = acc[cx];
        }
        __syncthreads();                                   // F2: part ready
        // ---- pool (dy,dx order verbatim) + i += c1 ----
        if (t < 70) {
            #pragma unroll
            for (int px = 0; px < 7; ++px) {
                float m = -1e30f;
                #pragma unroll
                for (int dy = 0; dy < 3; ++dy) {
                    const float* row = &part[(t * 3 + dy) * 21];
                    #pragma unroll
                    for (int dx = 0; dx < 3; ++dx)
                        m = fmaxf(m, row[3 * px + dx]);
                }
                i0r[px] = i0r[px] + (m + b1r);
            }
        }
        // no end barrier: part rewrite happens after next F1 (2 barriers away)
    }
}

// ----------------------------------------------------------- conv body ---
// conv2+pool+lif2. z0 comes from the fronts' tagged words (poll + expand);
// conv2 partials / reduction / lif2 / z2 publish verbatim round-11/13.
__device__ __forceinline__ void conv_body(int w, int b,
        const float* __restrict__ w2, const float* __restrict__ b2,
        const u64* __restrict__ az, u64* __restrict__ ac, float* smem) {
    const int ocStart2 = w * 9;
    const int nOc2 = (w == 7) ? 7 : 9;
    float* z0f  = smem;            // 1470
    float* part = smem + 1472;     // 2430
    float* red  = smem + 3904;     // 81
    unsigned int* zwL = (unsigned int*)(smem + 3988);  // 48

    const int t = threadIdx.x;
    const int lane = t & 63, wv = t >> 6;
    // z0 expansion map: e -> (word, bit): h=e/490, r=e%490
    int wI[6], bI[6];
    #pragma unroll
    for (int k = 0; k < 6; ++k) {
        int e = t + k * 256;
        if (e < 1470) {
            int hh = e / 490, r = e - 490 * hh;
            wI[k] = 16 * hh + (r >> 5);
            bI[k] = r & 31;
        } else { wI[k] = 0; bI[k] = 0; }
    }
    float v2 = 0.f, i2 = 0.f;
    float bias2 = (t < nOc2) ? b2[ocStart2 + t] : 0.f;
    if (t == 0) ast64(ac + w, ((u64)1 << 32));   // z2(0) = 0, tag 1
    __syncthreads();

    for (int tt = 0; tt < TSTEPS; ++tt) {
        // ---- A: poll z0(tt) words; expand to z0f ----
        if (wv == 0) {
            bool need = lane < 48;
            u64 wd = 0;
            for (;;) {
                if (need) wd = ald64(az + (size_t)tt * 48 + lane);
                bool ok = !need || (unsigned)(wd >> 32) == (unsigned)(tt + 1);
                if (__ballot(ok) == ~0ull) break;
                __builtin_amdgcn_s_sleep(1);
            }
            if (need) zwL[lane] = (unsigned)wd;
        }
        __syncthreads();                                   // B0: zwL ready
        #pragma unroll
        for (int k = 0; k < 6; ++k) {
            int e = t + k * 256;
            if (e < 1470) z0f[e] = ((zwL[wI[k]] >> bI[k]) & 1u) ? 1.f : 0.f;
        }
        __syncthreads();                                   // B1: z0f ready
        // ---- B: conv2 partials (verbatim) ----
        #pragma unroll
        for (int pass = 0; pass < 2; ++pass) {
            int u = t + pass * 256;
            if (u < nOc2 * 30) {
                int ol = u / 30, ic = u - ol * 30;
                float zw[49];
                #pragma unroll
                for (int j = 0; j < 49; ++j) zw[j] = z0f[ic * 49 + j];
                float a[9];
                #pragma unroll
                for (int p = 0; p < 9; ++p) a[p] = 0.f;
                const float* wb = w2 + (size_t)(ocStart2 + ol) * 750 + ic * 25;
                #pragma unroll
                for (int ky = 0; ky < 5; ++ky)
                    #pragma unroll
                    for (int kx = 0; kx < 5; ++kx) {
                        float wvv = wb[ky * 5 + kx];
                        #pragma unroll
                        for (int cy = 0; cy < 3; ++cy)
                            #pragma unroll
                            for (int cx = 0; cx < 3; ++cx)
                                a[cy * 3 + cx] = fmaf(zw[(cy + ky) * 7 + cx + kx], wvv, a[cy * 3 + cx]);
                    }
                #pragma unroll
                for (int p = 0; p < 9; ++p) part[u * 9 + p] = a[p];
            }
        }
        __syncthreads();                                   // B2: part ready
        if (t < nOc2 * 9) {
            int ol = t / 9, pos = t - ol * 9;
            float s2 = 0.f;
            for (int ic = 0; ic < 30; ++ic) s2 += part[(ol * 30 + ic) * 9 + pos];
            red[t] = s2;
        }
        __syncthreads();                                   // B3: red ready
        bool sp2 = false;
        if (t < nOc2) {
            float m = -1e30f;
            #pragma unroll
            for (int p = 0; p < 9; ++p) m = fmaxf(m, red[t * 9 + p]);
            float inp = m + bias2;
            float id2 = i2 - 0.2f * i2;
            i2 = id2 + inp;
            float vd2 = v2 + 0.1f * (i2 - v2);
            sp2 = (vd2 > 1.0f);
            v2 = sp2 ? 0.f : vd2;
        }
        if (tt + 1 < TSTEPS) {
            u64 mz2 = __ballot(sp2);
            if (t == 0)
                ast64(ac + (size_t)(tt + 1) * 8 + w,
                      (((u64)(tt + 2)) << 32) | (mz2 & 0x1ffull));
        }
    }
}

// --------------------------------------------------------- stripe body ---
// Round-13 verbatim (early-poll reverted).
template <int ROLE>
__device__ __forceinline__ void stripe_body(int b, int s,
        const float* __restrict__ catT,
        u64* __restrict__ arch,
        const u64* __restrict__ ac,
        float* smem) {
    constexpr int N    = ROLE ? HID2 : HID1;
    constexpr int K    = ROLE ? K2CAT : K1CAT;
    constexpr int SW   = N / 32;
    constexpr int NW   = N / 32;
    constexpr int NWT  = NW + 3;
    constexpr int N4   = N / 4;
    constexpr int COLS = ROLE ? 64 : 128;
    constexpr int QC   = COLS / 4;
    constexpr int S    = 256 / QC;
    constexpr int PSTR = COLS + 4;

    float* part = smem;                                    // <=1088
    unsigned short* list = (unsigned short*)(smem + 1088); // K2CAT u16
    unsigned int* maskw = (unsigned int*)(smem + 1088 + 547);
    unsigned int* wprefix = maskw + 40;

    const int t = threadIdx.x;
    const int lane = t & 63, wv = t >> 6;
    const int aid = t / QC, qid = t - (t / QC) * QC;
    const int q0 = s * QC;

    const float4* __restrict__ catT4 = (const float4*)catT;
    float v = 0.f, iacc = 0.f;

    if (wv == 0) {
        bool needc = (lane >= 40 && lane < 48);
        u64 cw = 0;
        for (;;) {
            if (needc) cw = ald64(ac + (lane - 40));
            bool ok = !needc || (unsigned)(cw >> 32) == 1u;
            if (__ballot(ok) == ~0ull) break;
            __builtin_amdgcn_s_sleep(1);
        }
        if (lane < NW) maskw[lane] = 0u;
        u64 lo = 0, hi = 0;
        #pragma unroll
        for (int w = 0; w < 8; ++w) {
            u64 p = (u64)(__shfl((unsigned)cw, 40 + w) & 0x1ffu);
            if (w < 7) lo |= p << (9 * w);
            else { lo |= (p & 1ull) << 63; hi = p >> 1; }
        }
        if (lane == 0) {
            maskw[NW] = (unsigned)lo; maskw[NW + 1] = (unsigned)(lo >> 32);
            maskw[NW + 2] = (unsigned)hi;
        }
        unsigned val = (lane < NWT) ? __popc(maskw[lane]) : 0u;
        #pragma unroll
        for (int d = 1; d < 64; d <<= 1) {
            unsigned u2 = __shfl_up(val, d);
            if (lane >= d) val += u2;
        }
        if (lane < NWT) wprefix[lane + 1] = val;
        if (lane == 0) wprefix[0] = 0u;
    }
    __syncthreads();
    int A = wprefix[NWT];
    for (int jj = t; jj < K; jj += 256) {
        unsigned m = maskw[jj >> 5];
        if ((m >> (jj & 31)) & 1u)
            list[wprefix[jj >> 5] + __popc(m & ((1u << (jj & 31)) - 1u))] = (unsigned short)jj;
    }
    __syncthreads();

    for (int tt = 0; tt < TSTEPS; ++tt) {
        float vd = v + 0.1f * (iacc - v);
        bool sp = (t < COLS) && (vd > 0.4f);
        float znew = sp ? 1.f : 0.f;
        if (t < COLS) v = sp ? 0.f : vd;
        u64 mz = __ballot(znew != 0.f);
        if (lane == 0 && wv < COLS / 64) {
            u64 tag = ((u64)(tt + 1)) << 32;
            u64* wslot = arch + (size_t)tt * SW + s * (COLS / 32) + wv * 2;
            ast64(wslot,     tag | (unsigned)(mz & 0xffffffffull));
            ast64(wslot + 1, tag | (unsigned)(mz >> 32));
        }
        float4 s0 = {0.f, 0.f, 0.f, 0.f}, s1 = s0, s2 = s0, s3 = s0;
        int idx = aid;
        for (; idx + 3 * S < A; idx += 4 * S) {
            s0 = f4add(s0, catT4[(size_t)list[idx]         * N4 + q0 + qid]);
            s1 = f4add(s1, catT4[(size_t)list[idx + S]     * N4 + q0 + qid]);
            s2 = f4add(s2, catT4[(size_t)list[idx + 2 * S] * N4 + q0 + qid]);
            s3 = f4add(s3, catT4[(size_t)list[idx + 3 * S] * N4 + q0 + qid]);
        }
        for (; idx < A; idx += S) s0 = f4add(s0, catT4[(size_t)list[idx] * N4 + q0 + qid]);
        s0 = f4add(f4add(s0, s1), f4add(s2, s3));
        *(float4*)(part + aid * PSTR + 4 * qid) = s0;
        __syncthreads();                                   // B1
        if (t < COLS) {
            float cur = 0.f;
            #pragma unroll
            for (int a = 0; a < S; ++a) cur += part[a * PSTR + t];
            iacc = iacc - 0.2f * iacc + cur;
        }
        if (tt + 1 >= TSTEPS) break;
        if (wv == 0) {
            bool needr = lane < SW;
            bool needc = (lane >= 40 && lane < 48);
            u64 wr = 0, wc = 0;
            for (;;) {
                if (needr) wr = ald64(arch + (size_t)tt * SW + lane);
                if (needc) wc = ald64(ac + (size_t)(tt + 1) * 8 + (lane - 40));
                bool ok = (!needr || (unsigned)(wr >> 32) == (unsigned)(tt + 1))
                       && (!needc || (unsigned)(wc >> 32) == (unsigned)(tt + 2));
                if (__ballot(ok) == ~0ull) break;
                __builtin_amdgcn_s_sleep(1);
            }
            if (needr) maskw[lane] = (unsigned)wr;
            u64 lo = 0, hi = 0;
            #pragma unroll
            for (int w = 0; w < 8; ++w) {
                u64 p = (u64)(__shfl((unsigned)wc, 40 + w) & 0x1ffu);
                if (w < 7) lo |= p << (9 * w);
                else { lo |= (p & 1ull) << 63; hi = p >> 1; }
            }
            if (lane == 0) {
                maskw[NW] = (unsigned)lo; maskw[NW + 1] = (unsigned)(lo >> 32);
                maskw[NW + 2] = (unsigned)hi;
            }
            unsigned val = (lane < NWT) ? __popc(maskw[lane]) : 0u;
            #pragma unroll
            for (int d = 1; d < 64; d <<= 1) {
                unsigned u2 = __shfl_up(val, d);
                if (lane >= d) val += u2;
            }
            if (lane < NWT) wprefix[lane + 1] = val;
            if (lane == 0) wprefix[0] = 0u;
        }
        __syncthreads();                                   // B2
        A = wprefix[NWT];
        for (int jj = t; jj < K; jj += 256) {
            unsigned m = maskw[jj >> 5];
            if ((m >> (jj & 31)) & 1u)
                list[wprefix[jj >> 5] + __popc(m & ((1u << (jj & 31)) - 1u))] = (unsigned short)jj;
        }
        __syncthreads();                                   // B3
    }
}

// --------------------------------------------------- merged reader body ---
__device__ __forceinline__ void reader_body(int b,
        const float* __restrict__ fc_out_w,
        const float* __restrict__ cl_fc_w,
        const u64* __restrict__ a1b, const u64* __restrict__ a0b,
        float* __restrict__ out, float* smem) {
    unsigned int* zw1 = (unsigned int*)smem;        // 32
    unsigned int* zw0 = (unsigned int*)smem + 32;   // 16
    float* wp1 = smem + 48;                         // 40
    float* wp0 = smem + 88;                         // 16
    float* mvals = smem + 104;                      // 10

    const int t = threadIdx.x;
    const int lane = t & 63, wv = t >> 6;
    const bool need1 = (wv == 0) && lane < 32;
    const bool need0 = (wv == 0) && lane >= 32 && lane < 48;
    float vli1 = 0.f, ili1 = 0.f, rmax1 = -1e30f;   // t < 10
    float vli0 = 0.f, ili0 = 0.f, rmax0 = -1e30f;   // t in [32,36)

    for (int tt = 0; tt < TSTEPS; ++tt) {
        if (wv == 0) {
            u64 w1v = 0, w0v = 0;
            for (;;) {
                if (need1) w1v = ald64(a1b + (size_t)tt * 32 + lane);
                if (need0) w0v = ald64(a0b + (size_t)tt * 16 + (lane - 32));
                bool ok = (!need1 || (unsigned)(w1v >> 32) == (unsigned)(tt + 1))
                       && (!need0 || (unsigned)(w0v >> 32) == (unsigned)(tt + 1));
                if (__ballot(ok) == ~0ull) break;
                __builtin_amdgcn_s_sleep(1);
            }
            if (need1) zw1[lane] = (unsigned)w1v;
            if (need0) zw0[lane - 32] = (unsigned)w0v;
        }
        __syncthreads();
        #pragma unroll
        for (int k = 0; k < 10; ++k) {
            unsigned bits = (zw1[(t * 4) >> 5] >> ((t * 4) & 31)) & 0xFu;
            float4 w4 = ((const float4*)cl_fc_w)[k * (HID2 / 4) + t];
            float p = (bits & 1u ? w4.x : 0.f) + (bits & 2u ? w4.y : 0.f)
                    + (bits & 4u ? w4.z : 0.f) + (bits & 8u ? w4.w : 0.f);
            #pragma unroll
            for (int off = 32; off; off >>= 1) p += __shfl_xor(p, off);
            if (lane == 0) wp1[k * 4 + wv] = p;
        }
        #pragma unroll
        for (int k = 0; k < 4; ++k) {
            unsigned bits = (zw0[(t * 2) >> 5] >> ((t * 2) & 31)) & 0x3u;
            float2 w2 = ((const float2*)fc_out_w)[k * (HID1 / 2) + t];
            float p = (bits & 1u ? w2.x : 0.f) + (bits & 2u ? w2.y : 0.f);
            #pragma unroll
            for (int off = 32; off; off >>= 1) p += __shfl_xor(p, off);
            if (lane == 0) wp0[k * 4 + wv] = p;
        }
        __syncthreads();
        if (t < 10) {
            float inp = wp1[t * 4] + wp1[t * 4 + 1] + wp1[t * 4 + 2] + wp1[t * 4 + 3];
            float vn = vli1 + 0.1f * (ili1 - vli1);
            ili1 = ili1 - 0.2f * ili1 + inp;
            vli1 = vn;
            rmax1 = fmaxf(rmax1, vn);
        }
        if (t >= 32 && t < 36) {
            int r = t - 32;
            float inp = wp0[r * 4] + wp0[r * 4 + 1] + wp0[r * 4 + 2] + wp0[r * 4 + 3];
            float vn = vli0 + 0.1f * (ili0 - vli0);
            ili0 = ili0 - 0.2f * ili0 + inp;
            vli0 = vn;
            rmax0 = fmaxf(rmax0, vn);
        }
    }
    if (t < 10) mvals[t] = rmax1;
    __syncthreads();
    if (t < 10) {
        float M = -1e30f;
        #pragma unroll
        for (int k = 0; k < 10; ++k) M = fmaxf(M, mvals[k]);
        float ssum = 0.f;
        #pragma unroll
        for (int k = 0; k < 10; ++k) ssum += expf(mvals[k] - M);
        out[BATCH * 4 + b * 10 + t] = mvals[t] - M - logf(ssum);
    }
    if (t >= 32 && t < 36) out[b * 4 + (t - 32)] = rmax0;
}

// -------------------------------------------------------------- fused ---
__global__ __launch_bounds__(256, 4) void snn_fused(
        const float* __restrict__ x,
        const float* __restrict__ w1, const float* __restrict__ b1,
        const float* __restrict__ w2, const float* __restrict__ b2,
        const float* __restrict__ fc_out_w, const float* __restrict__ cl_fc_w,
        const float* __restrict__ w1t, const float* __restrict__ w2t,
        u64* __restrict__ arch1, u64* __restrict__ arch0,
        u64* __restrict__ archc, u64* __restrict__ archz,
        float* __restrict__ out) {
    __shared__ float smem[7936];      // 31.7 KB; 4 WG/CU -> 127 KB/CU
    int bid = blockIdx.x;
    if (bid < 96) {                                     // fronts (batch-major)
        int h = bid >> 5, b = bid & 31;
        front_body(h, b, x, w1, b1, archz + (size_t)b * TSTEPS * 48, smem);
    } else if (bid < 352) {                             // conv2 (batch-major)
        int idx = bid - 96;
        int w = idx >> 5, b = idx & 31;
        conv_body(w, b, w2, b2, archz + (size_t)b * TSTEPS * 48,
                  archc + (size_t)b * TSTEPS * 8, smem);
    } else if (bid < 864) {                             // role-1 (stripe-major)
        int idx = bid - 352;
        int s = idx & 15, b = idx >> 4;
        stripe_body<1>(b, s, w2t, arch1 + (size_t)b * TSTEPS * 32,
                       archc + (size_t)b * TSTEPS * 8, smem);
    } else if (bid < 992) {                             // role-0 (stripe-major)
        int idx = bid - 864;
        int s = idx & 3, b = idx >> 2;
        stripe_body<0>(b, s, w1t, arch0 + (size_t)b * TSTEPS * 16,
                       archc + (size_t)b * TSTEPS * 8, smem);
    } else {                                            // merged readers
        int b = bid - 992;
        reader_body(b, fc_out_w, cl_fc_w,
                    arch1 + (size_t)b * TSTEPS * 32,
                    arch0 + (size_t)b * TSTEPS * 16, out, smem);
    }
}

// ---------------------------------------------------------------------------
extern "C" void kernel_launch(void* const* d_in, const int* in_sizes, int n_in,
                              void* d_out, int out_size, void* d_ws, size_t ws_size,
                              hipStream_t stream) {
    const float* x        = (const float*)d_in[0];
    const float* w1       = (const float*)d_in[1];
    const float* b1       = (const float*)d_in[2];
    const float* w2       = (const float*)d_in[3];
    const float* b2       = (const float*)d_in[4];
    const float* l1_in_w  = (const float*)d_in[5];
    const float* l1_rec_w = (const float*)d_in[6];
    const float* fc_out_w = (const float*)d_in[7];
    const float* cl_in_w  = (const float*)d_in[8];
    const float* cl_rec_w = (const float*)d_in[9];
    const float* cl_fc_w  = (const float*)d_in[10];
    float* out = (float*)d_out;

    u64* arch1  = (u64*)d_ws;
    u64* arch0  = arch1 + A1_U64;
    u64* archc  = arch0 + A0_U64;
    u64* archz  = archc + AC_U64;
    float* w1t  = (float*)(archz + AZ_U64);
    float* w2t  = w1t + N_W1T;

    setup_misc<<<dim3(256), dim3(256), 0, stream>>>(l1_in_w, l1_rec_w,
                                                    cl_in_w, cl_rec_w,
                                                    w1t, w2t, arch1);
    snn_fused<<<dim3(1024), dim3(256), 0, stream>>>(x, w1, b1, w2, b2,
                                                    fc_out_w, cl_fc_w, w1t, w2t,
                                                    arch1, arch0, archc, archz, out);
}

// Round 16
// 719.294 us; speedup vs baseline: 1.7927x; 1.7927x over previous
//
#include <hip/hip_runtime.h>
#include <math.h>

// ---------------------------------------------------------------------------
// SNN forward, Round-16: consolidation — exact round-13 structure (best
// verified: 719us) + the ONE isolated improvement from round-14: rec stripes
// stripe-major (bid%8 == s%8 -> per-XCD weight slice L2-resident; FETCH
// 38.3->32.3MB measured). Early-poll (r14 regression) and in-kernel conv1
// fronts (r15 regression: throughput work paced the latency loop) reverted.
//   setup -> conv1_pool (throughput, 2 frames/WG) -> snn_fused
//   (conv chains free-run ahead publishing tagged z2; rec stripes + readers).
// ---------------------------------------------------------------------------

#define BATCH 32
#define TSTEPS 150
#define C1N 1470
#define ZSEQN 70
#define HID1 512
#define HID2 1024
#define K1CAT 582           // rows: [rec(512) | conv(70)]
#define K2CAT 1094          // rows: [rec(1024) | conv(70)]

#define N_W1T  (K1CAT*HID1)           // 297,984
#define N_W2T  (K2CAT*HID2)           // 1,120,256

#define A1_U64  (BATCH*TSTEPS*32)     // 153,600
#define A0_U64  (BATCH*TSTEPS*16)     // 76,800
#define AC_U64  (BATCH*TSTEPS*8)      // 38,400
#define N_ARCH_U64 (A1_U64+A0_U64+AC_U64)   // 268,800 u64 = 2.15 MB

typedef unsigned long long u64;

// -------------------------------------------------------------------- K0 ---
__global__ void setup_misc(const float* __restrict__ l1_in_w,
                           const float* __restrict__ l1_rec_w,
                           const float* __restrict__ cl_in_w,
                           const float* __restrict__ cl_rec_w,
                           float* __restrict__ w1t,
                           float* __restrict__ w2t,
                           u64* __restrict__ arch) {
    int idx = blockIdx.x * blockDim.x + threadIdx.x;
    int stride = gridDim.x * blockDim.x;
    for (int e = idx; e < N_W1T; e += stride) {
        int j = e / HID1, o = e - j * HID1;
        w1t[e] = (j < HID1) ? l1_rec_w[o * HID1 + j] : l1_in_w[o * 70 + (j - HID1)];
    }
    for (int e = idx; e < N_W2T; e += stride) {
        int j = e / HID2, o = e - j * HID2;
        w2t[e] = (j < HID2) ? cl_rec_w[o * HID2 + j] : cl_in_w[o * 70 + (j - HID2)];
    }
    for (int e = idx; e < N_ARCH_U64; e += stride) arch[e] = 0ull;
}

// -------------------------------------------------------------------- K1 ---
// conv1 (2->30, 7x7, VALID) + maxpool3; TWO frames per WG. Verbatim r13.
__global__ __launch_bounds__(640) void conv1_pool(const float* __restrict__ x,
                                                  const float* __restrict__ w1,
                                                  const float* __restrict__ b1,
                                                  float* __restrict__ c1buf,
                                                  int b0) {
    __shared__ float img[2 * 34 * 34];
    __shared__ float w1s[30 * 2 * 49];
    __shared__ float crow[630 * 21];
    int tid = threadIdx.x;
    for (int e = tid; e < 2940; e += 640) w1s[e] = w1[e];
    #pragma unroll
    for (int k = 0; k < 2; ++k) {
        int f = blockIdx.x * 2 + k;           // f = bl*TSTEPS + ts
        int bl = f / TSTEPS, ts = f - bl * TSTEPS;
        const float* xin = x + ((size_t)(b0 + bl) * TSTEPS + ts) * 2312;
        __syncthreads();
        for (int e = tid; e < 2312; e += 640) img[e] = xin[e];
        __syncthreads();
        if (tid < 630) {
            int oc = tid / 21, cy = tid - oc * 21;
            float acc[21];
            #pragma unroll
            for (int j = 0; j < 21; ++j) acc[j] = 0.f;
            #pragma unroll
            for (int ic = 0; ic < 2; ++ic) {
                const float* irow0 = &img[ic * 1156];
                const float* wrow = &w1s[(oc * 2 + ic) * 49];
                #pragma unroll
                for (int ky = 0; ky < 7; ++ky) {
                    const float* ir = &irow0[(cy + ky) * 34];
                    float r[27];
                    #pragma unroll
                    for (int j = 0; j < 27; ++j) r[j] = ir[j];
                    #pragma unroll
                    for (int kx = 0; kx < 7; ++kx) {
                        float w = wrow[ky * 7 + kx];
                        #pragma unroll
                        for (int cx = 0; cx < 21; ++cx)
                            acc[cx] = fmaf(r[cx + kx], w, acc[cx]);
                    }
                }
            }
            #pragma unroll
            for (int cx = 0; cx < 21; ++cx) crow[tid * 21 + cx] = acc[cx];
        }
        __syncthreads();
        float* c1 = c1buf + (size_t)f * C1N;
        for (int p = tid; p < C1N; p += 640) {
            int oc = p / 49; int r = p - oc * 49; int py = r / 7, px = r - py * 7;
            float m = -1e30f;
            #pragma unroll
            for (int dy = 0; dy < 3; ++dy) {
                int rowid = oc * 21 + 3 * py + dy;
                #pragma unroll
                for (int dx = 0; dx < 3; ++dx)
                    m = fmaxf(m, crow[rowid * 21 + 3 * px + dx]);
            }
            c1[p] = m + b1[oc];
        }
    }
}

// ------------------------------------------------------------- helpers ---
__device__ __forceinline__ float4 f4add(float4 a, const float4 b) {
    a.x += b.x; a.y += b.y; a.z += b.z; a.w += b.w; return a;
}
__device__ __forceinline__ void ast64(u64* p, u64 v) {
    __hip_atomic_store(p, v, __ATOMIC_RELAXED, __HIP_MEMORY_SCOPE_AGENT);
}
__device__ __forceinline__ u64 ald64(const u64* p) {
    return __hip_atomic_load((u64*)p, __ATOMIC_RELAXED, __HIP_MEMORY_SCOPE_AGENT);
}

// ----------------------------------------------------------- conv body ---
// Verbatim round-13 conv chain.
__device__ __forceinline__ void conv_body(int w, int bl,
        const float* __restrict__ w2, const float* __restrict__ b2,
        const float* __restrict__ c1buf,
        u64* __restrict__ ac, float* smem) {
    const int ocStart2 = w * 9;
    const int nOc2 = (w == 7) ? 7 : 9;
    float* z0f  = smem;            // 1470
    float* part = smem + 1472;     // 2430
    float* red  = smem + 3904;     // 81

    const int t = threadIdx.x;
    float v0r[6], i0r[6], cf[6];
    #pragma unroll
    for (int k = 0; k < 6; ++k) { v0r[k] = 0.f; i0r[k] = 0.f; }
    float v2 = 0.f, i2 = 0.f;
    float bias2 = (t < nOc2) ? b2[ocStart2 + t] : 0.f;
    const float* c1 = c1buf + (size_t)bl * TSTEPS * C1N;
    #pragma unroll
    for (int k = 0; k < 6; ++k) {
        int e = t + k * 256;
        cf[k] = (e < C1N) ? c1[e] : 0.f;
    }
    if (t == 0) ast64(ac + w, ((u64)1 << 32));   // z2(0) = 0, tag 1
    __syncthreads();

    for (int tt = 0; tt < TSTEPS; ++tt) {
        float nf[6];
        bool h = (tt + 1 < TSTEPS);
        if (h) {
            const float* c1n = c1 + (size_t)(tt + 1) * C1N;
            #pragma unroll
            for (int k = 0; k < 6; ++k) {
                int e = t + k * 256;
                nf[k] = (e < C1N) ? c1n[e] : 0.f;
            }
        }
        #pragma unroll
        for (int k = 0; k < 6; ++k) {
            int e = t + k * 256;
            if (e < C1N) {
                float vd = v0r[k] + 0.1f * (i0r[k] - v0r[k]);
                bool sp = (vd > 1.0f);
                v0r[k] = sp ? 0.f : vd;
                i0r[k] = i0r[k] - 0.2f * i0r[k] + cf[k];
                z0f[e] = sp ? 1.f : 0.f;
            }
        }
        __syncthreads();                                   // B1: z0f ready
        #pragma unroll
        for (int pass = 0; pass < 2; ++pass) {
            int u = t + pass * 256;
            if (u < nOc2 * 30) {
                int ol = u / 30, ic = u - ol * 30;
                float zw[49];
                #pragma unroll
                for (int j = 0; j < 49; ++j) zw[j] = z0f[ic * 49 + j];
                float a[9];
                #pragma unroll
                for (int p = 0; p < 9; ++p) a[p] = 0.f;
                const float* wb = w2 + (size_t)(ocStart2 + ol) * 750 + ic * 25;
                #pragma unroll
                for (int ky = 0; ky < 5; ++ky)
                    #pragma unroll
                    for (int kx = 0; kx < 5; ++kx) {
                        float wvv = wb[ky * 5 + kx];
                        #pragma unroll
                        for (int cy = 0; cy < 3; ++cy)
                            #pragma unroll
                            for (int cx = 0; cx < 3; ++cx)
                                a[cy * 3 + cx] = fmaf(zw[(cy + ky) * 7 + cx + kx], wvv, a[cy * 3 + cx]);
                    }
                #pragma unroll
                for (int p = 0; p < 9; ++p) part[u * 9 + p] = a[p];
            }
        }
        __syncthreads();                                   // B2: part ready
        if (t < nOc2 * 9) {
            int ol = t / 9, pos = t - ol * 9;
            float s2 = 0.f;
            for (int ic = 0; ic < 30; ++ic) s2 += part[(ol * 30 + ic) * 9 + pos];
            red[t] = s2;
        }
        __syncthreads();                                   // B3: red ready
        bool sp2 = false;
        if (t < nOc2) {
            float m = -1e30f;
            #pragma unroll
            for (int p = 0; p < 9; ++p) m = fmaxf(m, red[t * 9 + p]);
            float inp = m + bias2;
            float id2 = i2 - 0.2f * i2;
            i2 = id2 + inp;
            float vd2 = v2 + 0.1f * (i2 - v2);
            sp2 = (vd2 > 1.0f);
            v2 = sp2 ? 0.f : vd2;
        }
        if (tt + 1 < TSTEPS) {
            u64 mz2 = __ballot(sp2);
            if (t == 0)
                ast64(ac + (size_t)(tt + 1) * 8 + w,
                      (((u64)(tt + 2)) << 32) | (mz2 & 0x1ffull));
        }
        #pragma unroll
        for (int k = 0; k < 6; ++k) cf[k] = nf[k];
    }
}

// --------------------------------------------------------- stripe body ---
// Verbatim round-13 (load-after-gather poll; no early-poll).
template <int ROLE>
__device__ __forceinline__ void stripe_body(int b, int s,
        const float* __restrict__ catT,
        u64* __restrict__ arch,
        const u64* __restrict__ ac,
        float* smem) {
    constexpr int N    = ROLE ? HID2 : HID1;
    constexpr int K    = ROLE ? K2CAT : K1CAT;
    constexpr int SW   = N / 32;
    constexpr int NW   = N / 32;
    constexpr int NWT  = NW + 3;
    constexpr int N4   = N / 4;
    constexpr int COLS = ROLE ? 64 : 128;
    constexpr int QC   = COLS / 4;
    constexpr int S    = 256 / QC;
    constexpr int PSTR = COLS + 4;

    float* part = smem;                                    // <=1088
    unsigned short* list = (unsigned short*)(smem + 1088); // K2CAT u16
    unsigned int* maskw = (unsigned int*)(smem + 1088 + 547);
    unsigned int* wprefix = maskw + 40;

    const int t = threadIdx.x;
    const int lane = t & 63, wv = t >> 6;
    const int aid = t / QC, qid = t - (t / QC) * QC;
    const int q0 = s * QC;

    const float4* __restrict__ catT4 = (const float4*)catT;
    float v = 0.f, iacc = 0.f;

    if (wv == 0) {
        bool needc = (lane >= 40 && lane < 48);
        u64 cw = 0;
        for (;;) {
            if (needc) cw = ald64(ac + (lane - 40));
            bool ok = !needc || (unsigned)(cw >> 32) == 1u;
            if (__ballot(ok) == ~0ull) break;
            __builtin_amdgcn_s_sleep(1);
        }
        if (lane < NW) maskw[lane] = 0u;
        u64 lo = 0, hi = 0;
        #pragma unroll
        for (int w = 0; w < 8; ++w) {
            u64 p = (u64)(__shfl((unsigned)cw, 40 + w) & 0x1ffu);
            if (w < 7) lo |= p << (9 * w);
            else { lo |= (p & 1ull) << 63; hi = p >> 1; }
        }
        if (lane == 0) {
            maskw[NW] = (unsigned)lo; maskw[NW + 1] = (unsigned)(lo >> 32);
            maskw[NW + 2] = (unsigned)hi;
        }
        unsigned val = (lane < NWT) ? __popc(maskw[lane]) : 0u;
        #pragma unroll
        for (int d = 1; d < 64; d <<= 1) {
            unsigned u2 = __shfl_up(val, d);
            if (lane >= d) val += u2;
        }
        if (lane < NWT) wprefix[lane + 1] = val;
        if (lane == 0) wprefix[0] = 0u;
    }
    __syncthreads();
    int A = wprefix[NWT];
    for (int jj = t; jj < K; jj += 256) {
        unsigned m = maskw[jj >> 5];
        if ((m >> (jj & 31)) & 1u)
            list[wprefix[jj >> 5] + __popc(m & ((1u << (jj & 31)) - 1u))] = (unsigned short)jj;
    }
    __syncthreads();

    for (int tt = 0; tt < TSTEPS; ++tt) {
        float vd = v + 0.1f * (iacc - v);
        bool sp = (t < COLS) && (vd > 0.4f);
        float znew = sp ? 1.f : 0.f;
        if (t < COLS) v = sp ? 0.f : vd;
        u64 mz = __ballot(znew != 0.f);
        if (lane == 0 && wv < COLS / 64) {
            u64 tag = ((u64)(tt + 1)) << 32;
            u64* wslot = arch + (size_t)tt * SW + s * (COLS / 32) + wv * 2;
            ast64(wslot,     tag | (unsigned)(mz & 0xffffffffull));
            ast64(wslot + 1, tag | (unsigned)(mz >> 32));
        }
        float4 s0 = {0.f, 0.f, 0.f, 0.f}, s1 = s0, s2 = s0, s3 = s0;
        int idx = aid;
        for (; idx + 3 * S < A; idx += 4 * S) {
            s0 = f4add(s0, catT4[(size_t)list[idx]         * N4 + q0 + qid]);
            s1 = f4add(s1, catT4[(size_t)list[idx + S]     * N4 + q0 + qid]);
            s2 = f4add(s2, catT4[(size_t)list[idx + 2 * S] * N4 + q0 + qid]);
            s3 = f4add(s3, catT4[(size_t)list[idx + 3 * S] * N4 + q0 + qid]);
        }
        for (; idx < A; idx += S) s0 = f4add(s0, catT4[(size_t)list[idx] * N4 + q0 + qid]);
        s0 = f4add(f4add(s0, s1), f4add(s2, s3));
        *(float4*)(part + aid * PSTR + 4 * qid) = s0;
        __syncthreads();                                   // B1
        if (t < COLS) {
            float cur = 0.f;
            #pragma unroll
            for (int a = 0; a < S; ++a) cur += part[a * PSTR + t];
            iacc = iacc - 0.2f * iacc + cur;
        }
        if (tt + 1 >= TSTEPS) break;
        if (wv == 0) {
            bool needr = lane < SW;
            bool needc = (lane >= 40 && lane < 48);
            u64 wr = 0, wc = 0;
            for (;;) {
                if (needr) wr = ald64(arch + (size_t)tt * SW + lane);
                if (needc) wc = ald64(ac + (size_t)(tt + 1) * 8 + (lane - 40));
                bool ok = (!needr || (unsigned)(wr >> 32) == (unsigned)(tt + 1))
                       && (!needc || (unsigned)(wc >> 32) == (unsigned)(tt + 2));
                if (__ballot(ok) == ~0ull) break;
                __builtin_amdgcn_s_sleep(1);
            }
            if (needr) maskw[lane] = (unsigned)wr;
            u64 lo = 0, hi = 0;
            #pragma unroll
            for (int w = 0; w < 8; ++w) {
                u64 p = (u64)(__shfl((unsigned)wc, 40 + w) & 0x1ffu);
                if (w < 7) lo |= p << (9 * w);
                else { lo |= (p & 1ull) << 63; hi = p >> 1; }
            }
            if (lane == 0) {
                maskw[NW] = (unsigned)lo; maskw[NW + 1] = (unsigned)(lo >> 32);
                maskw[NW + 2] = (unsigned)hi;
            }
            unsigned val = (lane < NWT) ? __popc(maskw[lane]) : 0u;
            #pragma unroll
            for (int d = 1; d < 64; d <<= 1) {
                unsigned u2 = __shfl_up(val, d);
                if (lane >= d) val += u2;
            }
            if (lane < NWT) wprefix[lane + 1] = val;
            if (lane == 0) wprefix[0] = 0u;
        }
        __syncthreads();                                   // B2
        A = wprefix[NWT];
        for (int jj = t; jj < K; jj += 256) {
            unsigned m = maskw[jj >> 5];
            if ((m >> (jj & 31)) & 1u)
                list[wprefix[jj >> 5] + __popc(m & ((1u << (jj & 31)) - 1u))] = (unsigned short)jj;
        }
        __syncthreads();                                   // B3
    }
}

// --------------------------------------------------------- reader body ---
// Verbatim round-13.
template <int ROLE>
__device__ __forceinline__ void readout_body(int b,
        const float* __restrict__ fcw,
        const u64* __restrict__ arch,
        float* __restrict__ out, float* smem) {
    constexpr int N  = ROLE ? HID2 : HID1;
    constexpr int SW = N / 32;
    constexpr int R  = ROLE ? 10 : 4;

    unsigned int* zw = (unsigned int*)smem;   // 32
    float* wpart = smem + 32;                 // 40
    float* mvals = smem + 72;                 // 10

    const int t = threadIdx.x;
    const int lane = t & 63, wv = t >> 6;
    float vli = 0.f, ili = 0.f, rmax = -1e30f;

    for (int tt = 0; tt < TSTEPS; ++tt) {
        if (wv == 0) {
            bool need = lane < SW;
            u64 w = 0;
            for (;;) {
                if (need) w = ald64(arch + (size_t)tt * SW + lane);
                bool ok = !need || (unsigned)(w >> 32) == (unsigned)(tt + 1);
                if (__ballot(ok) == ~0ull) break;
                __builtin_amdgcn_s_sleep(1);
            }
            if (need) zw[lane] = (unsigned)w;
        }
        __syncthreads();
        #pragma unroll
        for (int k = 0; k < R; ++k) {
            float p;
            if (ROLE) {
                unsigned bits = (zw[(t * 4) >> 5] >> ((t * 4) & 31)) & 0xFu;
                float4 w4 = ((const float4*)fcw)[k * (N / 4) + t];
                p = (bits & 1u ? w4.x : 0.f) + (bits & 2u ? w4.y : 0.f)
                  + (bits & 4u ? w4.z : 0.f) + (bits & 8u ? w4.w : 0.f);
            } else {
                unsigned bits = (zw[(t * 2) >> 5] >> ((t * 2) & 31)) & 0x3u;
                float2 w2 = ((const float2*)fcw)[k * (N / 2) + t];
                p = (bits & 1u ? w2.x : 0.f) + (bits & 2u ? w2.y : 0.f);
            }
            #pragma unroll
            for (int off = 32; off; off >>= 1) p += __shfl_xor(p, off);
            if (lane == 0) wpart[k * 4 + wv] = p;
        }
        __syncthreads();
        if (t < R) {
            float inp = wpart[t * 4] + wpart[t * 4 + 1] + wpart[t * 4 + 2] + wpart[t * 4 + 3];
            float vn = vli + 0.1f * (ili - vli);
            ili = ili - 0.2f * ili + inp;
            vli = vn;
            rmax = fmaxf(rmax, vn);
        }
    }
    if (ROLE) {
        if (t < 10) mvals[t] = rmax;
        __syncthreads();
        if (t < 10) {
            float M = -1e30f;
            #pragma unroll
            for (int k = 0; k < 10; ++k) M = fmaxf(M, mvals[k]);
            float ssum = 0.f;
            #pragma unroll
            for (int k = 0; k < 10; ++k) ssum += expf(mvals[k] - M);
            out[BATCH * 4 + b * 10 + t] = mvals[t] - M - logf(ssum);
        }
    } else if (t < 4) {
        out[b * 4 + t] = rmax;
    }
}

// -------------------------------------------------------------- fused ---
__global__ __launch_bounds__(256, 4) void snn_fused(
        const float* __restrict__ w2, const float* __restrict__ b2,
        const float* __restrict__ fc_out_w, const float* __restrict__ cl_fc_w,
        const float* __restrict__ w1t, const float* __restrict__ w2t,
        const float* __restrict__ c1buf,
        u64* __restrict__ arch1, u64* __restrict__ arch0,
        u64* __restrict__ archc,
        float* __restrict__ out, int b0, int BP) {
    __shared__ float smem[4096];      // 16.4 KB -> all WGs co-resident
    int bid = blockIdx.x;
    if (bid < 8 * BP) {                                 // conv chains (bl-major)
        int w = bid / BP, bl = bid - w * BP;
        int b = b0 + bl;
        conv_body(w, bl, w2, b2, c1buf,
                  archc + (size_t)b * TSTEPS * 8, smem);
    } else if (bid < 24 * BP) {                         // role-1 (stripe-major)
        int idx = bid - 8 * BP;
        int bl = idx >> 4, s = idx & 15;                // bid%8 tracks s%8
        int b = b0 + bl;
        stripe_body<1>(b, s, w2t, arch1 + (size_t)b * TSTEPS * 32,
                       archc + (size_t)b * TSTEPS * 8, smem);
    } else if (bid < 28 * BP) {                         // role-0 (stripe-major)
        int idx = bid - 24 * BP;
        int bl = idx >> 2, s = idx & 3;
        int b = b0 + bl;
        stripe_body<0>(b, s, w1t, arch0 + (size_t)b * TSTEPS * 16,
                       archc + (size_t)b * TSTEPS * 8, smem);
    } else if (bid < 29 * BP) {
        int b = b0 + (bid - 28 * BP);
        readout_body<1>(b, cl_fc_w, arch1 + (size_t)b * TSTEPS * 32, out, smem);
    } else {
        int b = b0 + (bid - 29 * BP);
        readout_body<0>(b, fc_out_w, arch0 + (size_t)b * TSTEPS * 16, out, smem);
    }
}

// ---------------------------------------------------------------------------
extern "C" void kernel_launch(void* const* d_in, const int* in_sizes, int n_in,
                              void* d_out, int out_size, void* d_ws, size_t ws_size,
                              hipStream_t stream) {
    const float* x        = (const float*)d_in[0];
    const float* w1       = (const float*)d_in[1];
    const float* b1       = (const float*)d_in[2];
    const float* w2       = (const float*)d_in[3];
    const float* b2       = (const float*)d_in[4];
    const float* l1_in_w  = (const float*)d_in[5];
    const float* l1_rec_w = (const float*)d_in[6];
    const float* fc_out_w = (const float*)d_in[7];
    const float* cl_in_w  = (const float*)d_in[8];
    const float* cl_rec_w = (const float*)d_in[9];
    const float* cl_fc_w  = (const float*)d_in[10];
    float* out = (float*)d_out;

    u64* arch1  = (u64*)d_ws;
    u64* arch0  = arch1 + A1_U64;
    u64* archc  = arch0 + A0_U64;
    float* w1t  = (float*)(archc + AC_U64);
    float* w2t  = w1t + N_W1T;
    float* c1buf = w2t + N_W2T;

    size_t head = 2 * (size_t)N_ARCH_U64 + N_W1T + N_W2T;   // in floats
    size_t avail = ws_size / 4;
    int BP = 4;
    if (head + (size_t)32 * TSTEPS * C1N <= avail) BP = 32;
    else if (head + (size_t)16 * TSTEPS * C1N <= avail) BP = 16;
    else if (head + (size_t)8 * TSTEPS * C1N <= avail) BP = 8;

    setup_misc<<<dim3(256), dim3(256), 0, stream>>>(l1_in_w, l1_rec_w,
                                                    cl_in_w, cl_rec_w,
                                                    w1t, w2t, arch1);
    for (int b0 = 0; b0 < BATCH; b0 += BP) {
        conv1_pool<<<dim3(BP * TSTEPS / 2), dim3(640), 0, stream>>>(x, w1, b1, c1buf, b0);
        snn_fused<<<dim3(30 * BP), dim3(256), 0, stream>>>(w2, b2, fc_out_w, cl_fc_w,
                                                           w1t, w2t, c1buf,
                                                           arch1, arch0, archc,
                                                           out, b0, BP);
    }
}